// Round 23
// baseline (46.276 us; speedup 1.0000x reference)
//
#include <hip/hip_runtime.h>
#include <hip/hip_fp16.h>
#include <math.h>

// SSIM loss: 1-WAVE BLOCKS, ZERO BARRIERS. Each 64-thread block computes a
// 16(col) x 32(row) output tile with the r19-validated per-wave pipeline:
//   stage 48x32 {x,y} f16 into wave-private LDS (6 KB; rows 42-47 and OOB
//   cells written as zeros every time -> no stale-pad hazard), 6 ds_read_b128
//   fragments (same-wave DS ordering = compiler-managed, no s_barrier),
//   12 banded K=32 H-MFMAs (Bh[j]=g[8am+j-cl-3]), register-chained 16x16x16
//   V-MFMAs (Av1[j]=g[4am+j-cl], Av2[j]=g[4am+j+16-cl]), SSIM on 8 reg px.
// Rationale: r12-r22 ledger shows ~40us plateau with pipes at {VALU 33%,
// MFMA 9%, HBM 26%} — latency-bound at 4 waves/SIMD, and launch_bounds
// cannot raise waves without spill (gfx950 unified VGPR/AGPR splits the cap:
// (256,8)->32, (256,6)->40 arch regs; r15/r16/r17). 1-wave blocks sidestep
// the bound entirely: residency set by actual usage (~5-6 waves/SIMD), no
// barrier convoy, no prefetch register state (staging regs die pre-compute).
// Block order: col-innermost + bijective XCD swizzle (24576%8==0) so the
// 2x column-halo stays in per-XCD L2; whole input (100MB) fits the 256MB L3,
// so halo re-reads cost L3 BW, not HBM.
// Reduction: atomicAdd into 1024 ws slots (spreads cache-line contention;
// ~24 atomics/line), then a tiny final-reduce kernel writes 1 - sum/N.

#define HH 512
#define WW 512
#define HW (HH*WW)
#define NPLANES 48
#define NBLK 24576             // 48 planes * 16 rowbands * 32 colblocks
#define NSLOT 1024

typedef _Float16 f16x8 __attribute__((ext_vector_type(8)));
typedef _Float16 f16x4 __attribute__((ext_vector_type(4)));
typedef float f32x4 __attribute__((ext_vector_type(4)));

#define ROW_B   64             // 32 f16 per staged row
#define PLANE_B 3072           // 48 rows
#define LDS_TOTAL 6144         // 2 planes

struct WParam { float A, B; };

__global__ void ssim_zero_ws(float* ws) {
    ws[blockIdx.x * 256 + threadIdx.x] = 0.f;   // 4 blocks x 256 = 1024
}

__global__ void ssim_final(const float* ws, float* out) {
    __shared__ float sm[4];
    const int tid = threadIdx.x;
    float s = ws[tid] + ws[tid + 256] + ws[tid + 512] + ws[tid + 768];
    for (int off = 32; off > 0; off >>= 1)
        s += __shfl_down(s, off, 64);
    if ((tid & 63) == 0) sm[tid >> 6] = s;
    __syncthreads();
    if (tid == 0) {
        const float invN = 1.0f / (float)((size_t)NPLANES * HH * WW);
        out[0] = 1.0f - (sm[0] + sm[1] + sm[2] + sm[3]) * invN;
    }
}

__global__ __launch_bounds__(64, 1)
void ssim_wave(const float* __restrict__ img, const float* __restrict__ tgt,
               float* __restrict__ ws, WParam wp) {
    __shared__ alignas(16) char lds[LDS_TOTAL];

    const int lane = threadIdx.x;       // 0..63 (one wave)
    const int cl   = lane & 15;
    const int am   = lane >> 4;
    const int sub  = lane >> 3;         // staging: row-in-group 0..7
    const int slot = lane & 7;          // staging: float4 col group 0..7

    // bijective XCD swizzle (NBLK % 8 == 0): chunk of 3072 per XCD
    const int orig = blockIdx.x;
    const int wg   = (orig & 7) * (NBLK / 8) + (orig >> 3);
    // decode col-innermost: consecutive wg share rows -> L2 halo reuse
    const int cb = wg & 31;
    const int t1 = wg >> 5;
    const int rb = t1 & 15;
    const int p  = t1 >> 4;
    const int R0 = rb * 32;
    const int C0 = cb * 16;
    const float* ip = img + (size_t)p * HW;
    const float* tp = tgt + (size_t)p * HW;

    // ---- per-lane weight fragments (validated r11-r22) ----
    f16x8 Bh;
    #pragma unroll
    for (int j = 0; j < 8; ++j) {
        int ih = 8*am + j - cl - 3;
        float t = (float)(ih - 5);
        Bh[j] = ((unsigned)ih <= 10u) ? (_Float16)(wp.A * exp2f(-wp.B*t*t))
                                      : (_Float16)0.f;
    }
    f16x4 Av1, Av2;
    #pragma unroll
    for (int j = 0; j < 4; ++j) {
        int k = 4*am + j;
        int i1 = k - cl;
        float w1 = (float)(i1 - 5);
        Av1[j] = ((unsigned)i1 <= 10u) ? (_Float16)(wp.A * exp2f(-wp.B*w1*w1))
                                       : (_Float16)0.f;
        int i2 = k + 16 - cl;
        float w2 = (float)(i2 - 5);
        Av2[j] = ((unsigned)i2 <= 10u) ? (_Float16)(wp.A * exp2f(-wp.B*w2*w2))
                                       : (_Float16)0.f;
    }

    // ---- stage rows 0..47 x cols 0..31 of {x,y}; zeros for pad/OOB ----
    const int gc  = C0 - 8 + slot * 4;
    const bool cok = ((unsigned)gc <= (unsigned)(WW - 4));
    #pragma unroll
    for (int t = 0; t < 6; ++t) {
        int r  = 8*t + sub;             // 0..47; rows 42-47 forced zero
        int gr = R0 - 5 + r;
        float4 xv = make_float4(0.f, 0.f, 0.f, 0.f), yv = xv;
        if (r < 42 && cok && (unsigned)gr < (unsigned)HH) {
            const size_t off = (size_t)gr * WW + gc;
            xv = *(const float4*)(ip + off);
            yv = *(const float4*)(tp + off);
        }
        f16x4 hx, hy;
        hx[0]=(_Float16)xv.x; hx[1]=(_Float16)xv.y;
        hx[2]=(_Float16)xv.z; hx[3]=(_Float16)xv.w;
        hy[0]=(_Float16)yv.x; hy[1]=(_Float16)yv.y;
        hy[2]=(_Float16)yv.z; hy[3]=(_Float16)yv.w;
        char* dst = lds + r * ROW_B + slot * 8;
        *(f16x4*)(dst)           = hx;
        *(f16x4*)(dst + PLANE_B) = hy;
    }
    // same-wave LDS write->read: compiler inserts the lgkmcnt ordering.

    // ---- fragments: rows 16mt+cl, k-bytes am*16 (full 32-col window) ----
    const int abase = cl * ROW_B + am * 16;
    f16x8 hx3[3], hy3[3];
    #pragma unroll
    for (int mt = 0; mt < 3; ++mt) {
        hx3[mt] = *(const f16x8*)(lds + (16*mt) * ROW_B + abase);
        hy3[mt] = *(const f16x8*)(lds + PLANE_B + (16*mt) * ROW_B + abase);
    }

    // ---- H-blur (12 banded K=32 MFMAs) + chained V-blur + SSIM ----
    const float C1 = 1e-4f, C2 = 9e-4f;
    float lsum = 0.f;
    f32x4 accv[4][2];
    #pragma unroll
    for (int q = 0; q < 4; ++q) {
        f32x4 Dh[3];
        #pragma unroll
        for (int mt = 0; mt < 3; ++mt) {
            f16x8 A = (q == 0) ? hx3[mt]
                    : (q == 1) ? hy3[mt]
                    : (q == 2) ? (f16x8)(hx3[mt]*hx3[mt] + hy3[mt]*hy3[mt])
                               : (f16x8)(hx3[mt]*hy3[mt]);
            f32x4 zz = {0.f, 0.f, 0.f, 0.f};
            Dh[mt] = __builtin_amdgcn_mfma_f32_16x16x32_f16(A, Bh, zz, 0, 0, 0);
        }
        #pragma unroll
        for (int mtv = 0; mtv < 2; ++mtv) {
            f16x4 B1, B2;
            #pragma unroll
            for (int j = 0; j < 4; ++j) {
                B1[j] = (_Float16)Dh[mtv][j];
                B2[j] = (_Float16)Dh[mtv+1][j];
            }
            f32x4 zz = {0.f, 0.f, 0.f, 0.f};
            f32x4 acc = __builtin_amdgcn_mfma_f32_16x16x16f16(Av2, B2, zz, 0, 0, 0);
            accv[q][mtv] = __builtin_amdgcn_mfma_f32_16x16x16f16(Av1, B1, acc, 0, 0, 0);
        }
    }
    #pragma unroll
    for (int mtv = 0; mtv < 2; ++mtv) {
        #pragma unroll
        for (int j = 0; j < 4; ++j) {
            float mu1 = accv[0][mtv][j], mu2 = accv[1][mtv][j];
            float bss = accv[2][mtv][j], bxy = accv[3][mtv][j];
            float mu1s = mu1*mu1, mu2s = mu2*mu2, mu12 = mu1*mu2;
            float ssum = bss - mu1s - mu2s;
            float s12  = bxy - mu12;
            float num = (2.f*mu12 + C1) * (2.f*s12 + C2);
            float den = (mu1s + mu2s + C1) * (ssum + C2);
            lsum = fmaf(num, __builtin_amdgcn_rcpf(den), lsum);
        }
    }

    // ---- wave reduction + one atomic into a spread slot ----
    for (int off = 32; off > 0; off >>= 1)
        lsum += __shfl_down(lsum, off, 64);
    if (lane == 0)
        atomicAdd(&ws[orig & (NSLOT - 1)], lsum);
}

extern "C" void kernel_launch(void* const* d_in, const int* in_sizes, int n_in,
                              void* d_out, int out_size, void* d_ws, size_t ws_size,
                              hipStream_t stream) {
    const float* img = (const float*)d_in[0];
    const float* tgt = (const float*)d_in[1];
    float* out = (float*)d_out;
    float* ws  = (float*)d_ws;

    // g[i] = exp(-(i-5)^2/4.5)/s = A * 2^(-B*(i-5)^2)
    double s = 0.0;
    for (int i = 0; i < 11; ++i) {
        double d = (double)(i - 5);
        s += exp(-(d * d) / 4.5);
    }
    WParam wp;
    wp.A = (float)(1.0 / s);
    wp.B = (float)(M_LOG2E / 4.5);

    ssim_zero_ws<<<4, 256, 0, stream>>>(ws);
    ssim_wave<<<NBLK, 64, 0, stream>>>(img, tgt, ws, wp);
    ssim_final<<<1, 256, 0, stream>>>(ws, out);
}

// Round 24
// 45.091 us; speedup vs baseline: 1.0263x; 1.0263x over previous
//
#include <hip/hip_runtime.h>
#include <hip/hip_fp16.h>
#include <math.h>

// SSIM loss: 2 INDEPENDENT WAVES PER BLOCK, ZERO BARRIERS.
// r23 showed 1-wave blocks cap at ~16 workgroups/CU (~56% occupancy) even
// with tiny LDS/VGPR. Packing 2 never-syncing waves per 128-thread block
// doubles the waves admitted under the workgroup cap: LDS-capped at
// 160KB/12.3KB = 13 blocks = 26 waves/CU (81%).
// Per wave (identical to r23's validated pipeline, absmax 0.0):
//   stage 48x32 {x,y} f16 into its PRIVATE 6KB LDS pane (rows 42-47 and
//   OOB cells written zero each time), 6 ds_read_b128 fragments (same-wave
//   DS ordering compiler-managed), 12 banded K=32 H-MFMAs
//   (Bh[j]=g[8am+j-cl-3]), register-chained 16x16x16 V-MFMAs
//   (Av1[j]=g[4am+j-cl], Av2[j]=g[4am+j+16-cl]), SSIM on 8 reg px,
//   wave-reduce, one atomicAdd into a spread ws slot.
// Block order: col-innermost decode + bijective XCD swizzle (12288%8==0)
// keeps the 2x col-halo in per-XCD L2; the 100MB input lives in the 256MB
// L3 across replays (r23: FETCH 49MB, HBM 11%).
// Session invariants: no launch-bounds wave-cap above usage (unified
// VGPR/AGPR split spills: r15/r16/r17); no dyn-indexed/shuffled fragment
// arrays (r21); coalesced 8-row x float4 staging loads (r13).

#define HH 512
#define WW 512
#define HW (HH*WW)
#define NPLANES 48
#define NBLK 12288             // 24576 wave-tiles / 2 waves per block
#define NSLOT 1024

typedef _Float16 f16x8 __attribute__((ext_vector_type(8)));
typedef _Float16 f16x4 __attribute__((ext_vector_type(4)));
typedef float f32x4 __attribute__((ext_vector_type(4)));

#define ROW_B   64             // 32 f16 per staged row
#define PLANE_B 3072           // 48 rows
#define PANE_B  6144           // 2 planes, per wave
#define LDS_TOTAL 12288        // 2 panes

struct WParam { float A, B; };

__global__ void ssim_zero_ws(float* ws) {
    ws[blockIdx.x * 256 + threadIdx.x] = 0.f;   // 4 blocks x 256 = 1024
}

__global__ void ssim_final(const float* ws, float* out) {
    __shared__ float sm[4];
    const int tid = threadIdx.x;
    float s = ws[tid] + ws[tid + 256] + ws[tid + 512] + ws[tid + 768];
    for (int off = 32; off > 0; off >>= 1)
        s += __shfl_down(s, off, 64);
    if ((tid & 63) == 0) sm[tid >> 6] = s;
    __syncthreads();
    if (tid == 0) {
        const float invN = 1.0f / (float)((size_t)NPLANES * HH * WW);
        out[0] = 1.0f - (sm[0] + sm[1] + sm[2] + sm[3]) * invN;
    }
}

__global__ __launch_bounds__(128, 1)
void ssim_wave(const float* __restrict__ img, const float* __restrict__ tgt,
               float* __restrict__ ws, WParam wp) {
    __shared__ alignas(16) char lds[LDS_TOTAL];

    const int tid  = threadIdx.x;
    const int wid  = tid >> 6;          // 0..1 (independent waves)
    const int lane = tid & 63;
    const int cl   = lane & 15;
    const int am   = lane >> 4;
    const int sub  = lane >> 3;         // staging: row-in-group 0..7
    const int slot = lane & 7;          // staging: float4 col group 0..7
    char* pane = lds + wid * PANE_B;

    // bijective XCD swizzle (NBLK % 8 == 0), then per-wave tile id
    const int orig  = blockIdx.x;
    const int wg2   = (orig & 7) * (NBLK / 8) + (orig >> 3);
    const int gwave = wg2 * 2 + wid;
    // col-innermost decode: consecutive gwave share rows -> L2 halo reuse
    const int cb = gwave & 31;
    const int t1 = gwave >> 5;
    const int rb = t1 & 15;
    const int p  = t1 >> 4;
    const int R0 = rb * 32;
    const int C0 = cb * 16;
    const float* ip = img + (size_t)p * HW;
    const float* tp = tgt + (size_t)p * HW;

    // ---- per-lane weight fragments (validated r11-r23) ----
    f16x8 Bh;
    #pragma unroll
    for (int j = 0; j < 8; ++j) {
        int ih = 8*am + j - cl - 3;
        float t = (float)(ih - 5);
        Bh[j] = ((unsigned)ih <= 10u) ? (_Float16)(wp.A * exp2f(-wp.B*t*t))
                                      : (_Float16)0.f;
    }
    f16x4 Av1, Av2;
    #pragma unroll
    for (int j = 0; j < 4; ++j) {
        int k = 4*am + j;
        int i1 = k - cl;
        float w1 = (float)(i1 - 5);
        Av1[j] = ((unsigned)i1 <= 10u) ? (_Float16)(wp.A * exp2f(-wp.B*w1*w1))
                                       : (_Float16)0.f;
        int i2 = k + 16 - cl;
        float w2 = (float)(i2 - 5);
        Av2[j] = ((unsigned)i2 <= 10u) ? (_Float16)(wp.A * exp2f(-wp.B*w2*w2))
                                       : (_Float16)0.f;
    }

    // ---- stage rows 0..47 x cols 0..31 of {x,y}; zeros for pad/OOB ----
    const int gc  = C0 - 8 + slot * 4;
    const bool cok = ((unsigned)gc <= (unsigned)(WW - 4));
    #pragma unroll
    for (int t = 0; t < 6; ++t) {
        int r  = 8*t + sub;             // 0..47; rows 42-47 forced zero
        int gr = R0 - 5 + r;
        float4 xv = make_float4(0.f, 0.f, 0.f, 0.f), yv = xv;
        if (r < 42 && cok && (unsigned)gr < (unsigned)HH) {
            const size_t off = (size_t)gr * WW + gc;
            xv = *(const float4*)(ip + off);
            yv = *(const float4*)(tp + off);
        }
        f16x4 hx, hy;
        hx[0]=(_Float16)xv.x; hx[1]=(_Float16)xv.y;
        hx[2]=(_Float16)xv.z; hx[3]=(_Float16)xv.w;
        hy[0]=(_Float16)yv.x; hy[1]=(_Float16)yv.y;
        hy[2]=(_Float16)yv.z; hy[3]=(_Float16)yv.w;
        char* dst = pane + r * ROW_B + slot * 8;
        *(f16x4*)(dst)           = hx;
        *(f16x4*)(dst + PLANE_B) = hy;
    }
    // same-wave LDS write->read: compiler inserts the lgkmcnt ordering.

    // ---- fragments: rows 16mt+cl, k-bytes am*16 (full 32-col window) ----
    const int abase = cl * ROW_B + am * 16;
    f16x8 hx3[3], hy3[3];
    #pragma unroll
    for (int mt = 0; mt < 3; ++mt) {
        hx3[mt] = *(const f16x8*)(pane + (16*mt) * ROW_B + abase);
        hy3[mt] = *(const f16x8*)(pane + PLANE_B + (16*mt) * ROW_B + abase);
    }

    // ---- H-blur (12 banded K=32 MFMAs) + chained V-blur + SSIM ----
    const float C1 = 1e-4f, C2 = 9e-4f;
    float lsum = 0.f;
    f32x4 accv[4][2];
    #pragma unroll
    for (int q = 0; q < 4; ++q) {
        f32x4 Dh[3];
        #pragma unroll
        for (int mt = 0; mt < 3; ++mt) {
            f16x8 A = (q == 0) ? hx3[mt]
                    : (q == 1) ? hy3[mt]
                    : (q == 2) ? (f16x8)(hx3[mt]*hx3[mt] + hy3[mt]*hy3[mt])
                               : (f16x8)(hx3[mt]*hy3[mt]);
            f32x4 zz = {0.f, 0.f, 0.f, 0.f};
            Dh[mt] = __builtin_amdgcn_mfma_f32_16x16x32_f16(A, Bh, zz, 0, 0, 0);
        }
        #pragma unroll
        for (int mtv = 0; mtv < 2; ++mtv) {
            f16x4 B1, B2;
            #pragma unroll
            for (int j = 0; j < 4; ++j) {
                B1[j] = (_Float16)Dh[mtv][j];
                B2[j] = (_Float16)Dh[mtv+1][j];
            }
            f32x4 zz = {0.f, 0.f, 0.f, 0.f};
            f32x4 acc = __builtin_amdgcn_mfma_f32_16x16x16f16(Av2, B2, zz, 0, 0, 0);
            accv[q][mtv] = __builtin_amdgcn_mfma_f32_16x16x16f16(Av1, B1, acc, 0, 0, 0);
        }
    }
    #pragma unroll
    for (int mtv = 0; mtv < 2; ++mtv) {
        #pragma unroll
        for (int j = 0; j < 4; ++j) {
            float mu1 = accv[0][mtv][j], mu2 = accv[1][mtv][j];
            float bss = accv[2][mtv][j], bxy = accv[3][mtv][j];
            float mu1s = mu1*mu1, mu2s = mu2*mu2, mu12 = mu1*mu2;
            float ssum = bss - mu1s - mu2s;
            float s12  = bxy - mu12;
            float num = (2.f*mu12 + C1) * (2.f*s12 + C2);
            float den = (mu1s + mu2s + C1) * (ssum + C2);
            lsum = fmaf(num, __builtin_amdgcn_rcpf(den), lsum);
        }
    }

    // ---- wave reduction + one atomic into a spread slot ----
    for (int off = 32; off > 0; off >>= 1)
        lsum += __shfl_down(lsum, off, 64);
    if (lane == 0)
        atomicAdd(&ws[(orig * 2 + wid) & (NSLOT - 1)], lsum);
}

extern "C" void kernel_launch(void* const* d_in, const int* in_sizes, int n_in,
                              void* d_out, int out_size, void* d_ws, size_t ws_size,
                              hipStream_t stream) {
    const float* img = (const float*)d_in[0];
    const float* tgt = (const float*)d_in[1];
    float* out = (float*)d_out;
    float* ws  = (float*)d_ws;

    // g[i] = exp(-(i-5)^2/4.5)/s = A * 2^(-B*(i-5)^2)
    double s = 0.0;
    for (int i = 0; i < 11; ++i) {
        double d = (double)(i - 5);
        s += exp(-(d * d) / 4.5);
    }
    WParam wp;
    wp.A = (float)(1.0 / s);
    wp.B = (float)(M_LOG2E / 4.5);

    ssim_zero_ws<<<4, 256, 0, stream>>>(ws);
    ssim_wave<<<NBLK, 128, 0, stream>>>(img, tgt, ws, wp);
    ssim_final<<<1, 256, 0, stream>>>(ws, out);
}

// Round 25
// 40.306 us; speedup vs baseline: 1.1481x; 1.1187x over previous
//
#include <hip/hip_runtime.h>
#include <hip/hip_fp16.h>
#include <math.h>

// SSIM loss — FINAL (champion: r19/r22, 40.2-40.3us, absmax 0.0, x3 repro).
// Coalesced LDS staging + register-chained MFMA blurs + double-buffered
// LDS ping-pong -> 1 barrier/tile.
// Per 64x32 tile:
//   ph1: write prefetched {x,y} regs as f16 planes into buf[g&1];
//        issue next tile's global loads (in flight across raw s_barrier).
//   ONE barrier (lgkmcnt(0)+s_barrier+sched_barrier(0)).
//   compute (per wave, cols 16w..16w+15, reads buf[g&1], NO LDS writes):
//     6 ds_read_b128 -> s,p in packed f16 -> 12 banded K=32 H-MFMAs
//     (Bh[j]=g[8am+j-cl-3]) -> V-blur register-chained 16x16x16
//     (Av1[j]=g[4am+j-cl], Av2[j]=g[4am+j+16-cl]) -> SSIM on 8 reg px.
//   Next iteration writes the OTHER buffer: reads of buf[q] (iter g-2)
//   complete at lgkmcnt(0) before barrier(g-1) < writes of buf[q] (iter g).
// Session ledger (why this is the floor for this structure):
//  - (256,4) launch bounds mandatory: gfx950 unified VGPR/AGPR budget under
//    (256,6)/(256,8) splits to 40/32 arch regs -> 100-300MB scratch spill,
//    3x slowdown (r15/r16/r17).
//  - No shufflevector/dyn-indexing on fragment arrays (r21: 109MB scratch).
//  - Grid 1024 = 4/CU; 8/CU assigned regresses (r18: halo-reuse loss).
//  - Per-lane scattered global loads destroy coalescing (r13: 3.3x).
//  - Zero-barrier wave-private variants: 45-46us (r23/r24) — staging
//    redundancy eats the occupancy gain; ~16 wg/CU cap binds.
//  - Barriers 3->2->1, pipelined frag reads, fused V-MFMA: all flat/worse.
//  Plateau: ~4-5 waves/SIMD x ~3K-cyc dependency chain; no pipe >33%.

#define HH 512
#define WW 512
#define HW (HH*WW)
#define NPLANES 48
#define G_TILES 6
#define NBLOCKS 1024           // 6144 tiles / 6

typedef _Float16 f16x8 __attribute__((ext_vector_type(8)));
typedef _Float16 f16x4 __attribute__((ext_vector_type(4)));
typedef float f32x4 __attribute__((ext_vector_type(4)));

#define RAW_STRIDE 208         // bytes per staged row (104 f16; 80 used)
#define RAW_PLANE  9984        // 48*208; x at 0, y at RAW_PLANE
#define BUF_B      19968       // one buffer: 2 planes
#define LDS_TOTAL  39936       // 2 buffers (ping-pong)

struct WParam { float A, B; };

__global__ void ssim_init_out(float* out) { out[0] = 1.0f; }

__device__ __forceinline__ void barrier_nodrain() {
    asm volatile("s_waitcnt lgkmcnt(0)" ::: "memory");
    __builtin_amdgcn_s_barrier();
    __builtin_amdgcn_sched_barrier(0);
}

__global__ __launch_bounds__(256, 4)
void ssim_mfma(const float* __restrict__ img, const float* __restrict__ tgt,
               float* __restrict__ out, WParam wp) {
    __shared__ alignas(16) char lds[LDS_TOTAL];
    __shared__ float wsum[4];

    const int tid  = threadIdx.x;
    const int wid  = tid >> 6;
    const int lane = tid & 63;
    const int cl   = lane & 15;
    const int am   = lane >> 4;

    // fixed 2 staging items per thread (420 = 256 + 164)
    const int it0 = tid,       ir0 = it0 / 10, ig0 = it0 - 10 * ir0;
    const int it1 = tid + 256, ir1 = it1 / 10, ig1 = it1 - 10 * ir1;
    const bool has1 = (tid < 164);

    float4 Xa[2], Xb[2], Ya[2], Yb[2];

    auto load_tile = [&](int tlin) {
        const int p   = tlin >> 7;
        const int rem = tlin & 127;
        const int R0  = (rem >> 3) * 32;
        const int C0  = (rem & 7) * 64;
        const float* ip = img + (size_t)p * HW;
        const float* tp = tgt + (size_t)p * HW;
        #pragma unroll
        for (int s = 0; s < 2; ++s) {
            if (s == 1 && !has1) break;
            int r   = s ? ir1 : ir0;
            int grp = s ? ig1 : ig0;
            int gr  = R0 - 5 + r;
            int gc0 = C0 - 8 + grp * 8;
            float4 xa = make_float4(0.f,0.f,0.f,0.f), xb = xa, ya = xa, yb = xa;
            if ((unsigned)gr < (unsigned)HH) {
                const float* xr = ip + (size_t)gr * WW;
                const float* yr = tp + (size_t)gr * WW;
                if ((unsigned)gc0 <= (unsigned)(WW - 4)) {
                    xa = *(const float4*)(xr + gc0);
                    ya = *(const float4*)(yr + gc0);
                }
                if ((unsigned)(gc0 + 4) <= (unsigned)(WW - 4)) {
                    xb = *(const float4*)(xr + gc0 + 4);
                    yb = *(const float4*)(yr + gc0 + 4);
                }
            }
            Xa[s] = xa; Xb[s] = xb; Ya[s] = ya; Yb[s] = yb;
        }
    };

    auto write_tile = [&](char* buf) {
        #pragma unroll
        for (int s = 0; s < 2; ++s) {
            if (s == 1 && !has1) break;
            int r   = s ? ir1 : ir0;
            int grp = s ? ig1 : ig0;
            f16x8 hx, hy;
            hx[0]=(_Float16)Xa[s].x; hx[1]=(_Float16)Xa[s].y;
            hx[2]=(_Float16)Xa[s].z; hx[3]=(_Float16)Xa[s].w;
            hx[4]=(_Float16)Xb[s].x; hx[5]=(_Float16)Xb[s].y;
            hx[6]=(_Float16)Xb[s].z; hx[7]=(_Float16)Xb[s].w;
            hy[0]=(_Float16)Ya[s].x; hy[1]=(_Float16)Ya[s].y;
            hy[2]=(_Float16)Ya[s].z; hy[3]=(_Float16)Ya[s].w;
            hy[4]=(_Float16)Yb[s].x; hy[5]=(_Float16)Yb[s].y;
            hy[6]=(_Float16)Yb[s].z; hy[7]=(_Float16)Yb[s].w;
            char* base = buf + r * RAW_STRIDE + grp * 16;
            *(f16x8*)(base + 0*RAW_PLANE) = hx;
            *(f16x8*)(base + 1*RAW_PLANE) = hy;
        }
    };

    const int base_t = blockIdx.x * G_TILES;
    load_tile(base_t);                 // prologue prefetch (overlaps init)

    // ---- one-time LDS zero-init, BOTH buffers (pad regions stay zero) ----
    for (int i = tid; i < LDS_TOTAL / 4; i += 256)
        ((float*)lds)[i] = 0.f;

    // ---- per-lane weight fragments ----
    f16x8 Bh;
    #pragma unroll
    for (int j = 0; j < 8; ++j) {
        int ih = 8*am + j - cl - 3;
        float t = (float)(ih - 5);
        Bh[j] = ((unsigned)ih <= 10u) ? (_Float16)(wp.A * exp2f(-wp.B*t*t))
                                      : (_Float16)0.f;
    }
    f16x4 Av1, Av2;
    #pragma unroll
    for (int j = 0; j < 4; ++j) {
        int k = 4*am + j;
        int i1 = k - cl;
        float t1 = (float)(i1 - 5);
        Av1[j] = ((unsigned)i1 <= 10u) ? (_Float16)(wp.A * exp2f(-wp.B*t1*t1))
                                       : (_Float16)0.f;
        int i2 = k + 16 - cl;
        float t2 = (float)(i2 - 5);
        Av2[j] = ((unsigned)i2 <= 10u) ? (_Float16)(wp.A * exp2f(-wp.B*t2*t2))
                                       : (_Float16)0.f;
    }
    __syncthreads();

    const float C1 = 1e-4f, C2 = 9e-4f;
    float lsum = 0.f;

    for (int g = 0; g < G_TILES; ++g) {
        char* buf = lds + (g & 1) * BUF_B;

        // ---- phase 1: write prefetched tile to buf; issue next prefetch ----
        write_tile(buf);
        if (g + 1 < G_TILES) load_tile(base_t + g + 1);
        barrier_nodrain();             // the ONLY barrier in the loop

        // ---- compute: all-register H+V blur + SSIM (no LDS writes) ----
        {
            const int abase = cl * RAW_STRIDE + 32 * wid + am * 16;
            f16x8 hx3[3], hy3[3];
            #pragma unroll
            for (int mt = 0; mt < 3; ++mt) {
                hx3[mt] = *(const f16x8*)(buf + (16*mt) * RAW_STRIDE + abase);
                hy3[mt] = *(const f16x8*)(buf + RAW_PLANE + (16*mt) * RAW_STRIDE + abase);
            }

            f32x4 accv[4][2];
            #pragma unroll
            for (int q = 0; q < 4; ++q) {
                f32x4 Dh[3];
                #pragma unroll
                for (int mt = 0; mt < 3; ++mt) {
                    f16x8 A = (q == 0) ? hx3[mt]
                            : (q == 1) ? hy3[mt]
                            : (q == 2) ? (f16x8)(hx3[mt]*hx3[mt] + hy3[mt]*hy3[mt])
                                       : (f16x8)(hx3[mt]*hy3[mt]);
                    f32x4 zz = {0.f, 0.f, 0.f, 0.f};
                    Dh[mt] = __builtin_amdgcn_mfma_f32_16x16x32_f16(A, Bh, zz, 0, 0, 0);
                }
                #pragma unroll
                for (int mtv = 0; mtv < 2; ++mtv) {
                    f16x4 B1, B2;
                    #pragma unroll
                    for (int j = 0; j < 4; ++j) {
                        B1[j] = (_Float16)Dh[mtv][j];
                        B2[j] = (_Float16)Dh[mtv+1][j];
                    }
                    f32x4 zz = {0.f, 0.f, 0.f, 0.f};
                    f32x4 acc = __builtin_amdgcn_mfma_f32_16x16x16f16(Av2, B2, zz, 0, 0, 0);
                    accv[q][mtv] = __builtin_amdgcn_mfma_f32_16x16x16f16(Av1, B1, acc, 0, 0, 0);
                }
            }

            #pragma unroll
            for (int mtv = 0; mtv < 2; ++mtv) {
                #pragma unroll
                for (int j = 0; j < 4; ++j) {
                    float mu1 = accv[0][mtv][j], mu2 = accv[1][mtv][j];
                    float bss = accv[2][mtv][j], bxy = accv[3][mtv][j];
                    float mu1s = mu1*mu1, mu2s = mu2*mu2, mu12 = mu1*mu2;
                    float ssum = bss - mu1s - mu2s;
                    float s12  = bxy - mu12;
                    float num = (2.f*mu12 + C1) * (2.f*s12 + C2);
                    float den = (mu1s + mu2s + C1) * (ssum + C2);
                    lsum = fmaf(num, __builtin_amdgcn_rcpf(den), lsum);
                }
            }
        }
        // no trailing barrier: next iteration writes the OTHER buffer
    }

    // ---- block reduction + one atomic ----
    for (int off = 32; off > 0; off >>= 1)
        lsum += __shfl_down(lsum, off, 64);
    if (lane == 0) wsum[wid] = lsum;
    __syncthreads();
    if (tid == 0) {
        float bsum = wsum[0] + wsum[1] + wsum[2] + wsum[3];
        const float invN = 1.0f / (float)((size_t)NPLANES * HH * WW);
        atomicAdd(out, -bsum * invN);
    }
}

extern "C" void kernel_launch(void* const* d_in, const int* in_sizes, int n_in,
                              void* d_out, int out_size, void* d_ws, size_t ws_size,
                              hipStream_t stream) {
    const float* img = (const float*)d_in[0];
    const float* tgt = (const float*)d_in[1];
    float* out = (float*)d_out;

    // g[i] = exp(-(i-5)^2/4.5)/s = A * 2^(-B*(i-5)^2)
    double s = 0.0;
    for (int i = 0; i < 11; ++i) {
        double d = (double)(i - 5);
        s += exp(-(d * d) / 4.5);
    }
    WParam wp;
    wp.A = (float)(1.0 / s);
    wp.B = (float)(M_LOG2E / 4.5);

    ssim_init_out<<<1, 1, 0, stream>>>(out);
    ssim_mfma<<<NBLOCKS, 256, 0, stream>>>(img, tgt, out, wp);
}

// Round 26
// 38.549 us; speedup vs baseline: 1.2004x; 1.0456x over previous
//
#include <hip/hip_runtime.h>
#include <hip/hip_fp16.h>
#include <math.h>

// SSIM loss — champion (r19/r22/r25, 40.3us x4 repro, absmax 0.0) + T1
// bijective XCD-aware block swizzle (the single remaining spill-free lever).
// Mechanism: default dispatch round-robins blockIdx across the 8 XCDs, so
// halo-sharing neighbor blocks land on DIFFERENT per-XCD L2s. The swizzle
// wg=(orig&7)*128+(orig>>3) (bijective: 1024%8==0) gives each XCD a
// contiguous chunk of the tile space -> row/col halos hit the local L2
// (r23/r24 measured FETCH 87->49MB with this ordering on the wave-private
// variant). HBM is at 26% (not binding), but L2-hit loads cut average load
// latency ~4.5x, trimming latency leakage in the prefetch window.
// Everything else byte-identical to the champion:
//   ph1: write prefetched {x,y} regs as f16 planes into buf[g&1];
//        issue next tile's global loads (in flight across raw s_barrier).
//   ONE barrier (lgkmcnt(0)+s_barrier+sched_barrier(0)).
//   compute: 6 ds_read_b128 -> s,p packed f16 -> 12 banded K=32 H-MFMAs
//     (Bh[j]=g[8am+j-cl-3]) -> register-chained 16x16x16 V-MFMAs
//     (Av1[j]=g[4am+j-cl], Av2[j]=g[4am+j+16-cl]) -> SSIM on 8 reg px.
// Session ledger: (256,4) launch bounds mandatory (unified VGPR/AGPR spill
// cliff, r15/r16/r17); no dyn-indexed/shuffled frag arrays (r21); 4/CU
// assigned grid (r18); coalesced staging (r13); barriers 3->2->1,
// pipelining, fused V-MFMA, wave-private variants: all flat/worse.

#define HH 512
#define WW 512
#define HW (HH*WW)
#define NPLANES 48
#define G_TILES 6
#define NBLOCKS 1024           // 6144 tiles / 6

typedef _Float16 f16x8 __attribute__((ext_vector_type(8)));
typedef _Float16 f16x4 __attribute__((ext_vector_type(4)));
typedef float f32x4 __attribute__((ext_vector_type(4)));

#define RAW_STRIDE 208         // bytes per staged row (104 f16; 80 used)
#define RAW_PLANE  9984        // 48*208; x at 0, y at RAW_PLANE
#define BUF_B      19968       // one buffer: 2 planes
#define LDS_TOTAL  39936       // 2 buffers (ping-pong)

struct WParam { float A, B; };

__global__ void ssim_init_out(float* out) { out[0] = 1.0f; }

__device__ __forceinline__ void barrier_nodrain() {
    asm volatile("s_waitcnt lgkmcnt(0)" ::: "memory");
    __builtin_amdgcn_s_barrier();
    __builtin_amdgcn_sched_barrier(0);
}

__global__ __launch_bounds__(256, 4)
void ssim_mfma(const float* __restrict__ img, const float* __restrict__ tgt,
               float* __restrict__ out, WParam wp) {
    __shared__ alignas(16) char lds[LDS_TOTAL];
    __shared__ float wsum[4];

    const int tid  = threadIdx.x;
    const int wid  = tid >> 6;
    const int lane = tid & 63;
    const int cl   = lane & 15;
    const int am   = lane >> 4;

    // fixed 2 staging items per thread (420 = 256 + 164)
    const int it0 = tid,       ir0 = it0 / 10, ig0 = it0 - 10 * ir0;
    const int it1 = tid + 256, ir1 = it1 / 10, ig1 = it1 - 10 * ig1 * 0 - 10 * ir1;
    const bool has1 = (tid < 164);

    float4 Xa[2], Xb[2], Ya[2], Yb[2];

    auto load_tile = [&](int tlin) {
        const int p   = tlin >> 7;
        const int rem = tlin & 127;
        const int R0  = (rem >> 3) * 32;
        const int C0  = (rem & 7) * 64;
        const float* ip = img + (size_t)p * HW;
        const float* tp = tgt + (size_t)p * HW;
        #pragma unroll
        for (int s = 0; s < 2; ++s) {
            if (s == 1 && !has1) break;
            int r   = s ? ir1 : ir0;
            int grp = s ? ig1 : ig0;
            int gr  = R0 - 5 + r;
            int gc0 = C0 - 8 + grp * 8;
            float4 xa = make_float4(0.f,0.f,0.f,0.f), xb = xa, ya = xa, yb = xa;
            if ((unsigned)gr < (unsigned)HH) {
                const float* xr = ip + (size_t)gr * WW;
                const float* yr = tp + (size_t)gr * WW;
                if ((unsigned)gc0 <= (unsigned)(WW - 4)) {
                    xa = *(const float4*)(xr + gc0);
                    ya = *(const float4*)(yr + gc0);
                }
                if ((unsigned)(gc0 + 4) <= (unsigned)(WW - 4)) {
                    xb = *(const float4*)(xr + gc0 + 4);
                    yb = *(const float4*)(yr + gc0 + 4);
                }
            }
            Xa[s] = xa; Xb[s] = xb; Ya[s] = ya; Yb[s] = yb;
        }
    };

    auto write_tile = [&](char* buf) {
        #pragma unroll
        for (int s = 0; s < 2; ++s) {
            if (s == 1 && !has1) break;
            int r   = s ? ir1 : ir0;
            int grp = s ? ig1 : ig0;
            f16x8 hx, hy;
            hx[0]=(_Float16)Xa[s].x; hx[1]=(_Float16)Xa[s].y;
            hx[2]=(_Float16)Xa[s].z; hx[3]=(_Float16)Xa[s].w;
            hx[4]=(_Float16)Xb[s].x; hx[5]=(_Float16)Xb[s].y;
            hx[6]=(_Float16)Xb[s].z; hx[7]=(_Float16)Xb[s].w;
            hy[0]=(_Float16)Ya[s].x; hy[1]=(_Float16)Ya[s].y;
            hy[2]=(_Float16)Ya[s].z; hy[3]=(_Float16)Ya[s].w;
            hy[4]=(_Float16)Yb[s].x; hy[5]=(_Float16)Yb[s].y;
            hy[6]=(_Float16)Yb[s].z; hy[7]=(_Float16)Yb[s].w;
            char* base = buf + r * RAW_STRIDE + grp * 16;
            *(f16x8*)(base + 0*RAW_PLANE) = hx;
            *(f16x8*)(base + 1*RAW_PLANE) = hy;
        }
    };

    // T1: bijective XCD swizzle (NBLOCKS % 8 == 0) — same-XCD blocks get
    // consecutive tile ranges -> halo reuse in the local L2.
    const int orig = blockIdx.x;
    const int wg   = (orig & 7) * (NBLOCKS / 8) + (orig >> 3);
    const int base_t = wg * G_TILES;
    load_tile(base_t);                 // prologue prefetch (overlaps init)

    // ---- one-time LDS zero-init, BOTH buffers (pad regions stay zero) ----
    for (int i = tid; i < LDS_TOTAL / 4; i += 256)
        ((float*)lds)[i] = 0.f;

    // ---- per-lane weight fragments ----
    f16x8 Bh;
    #pragma unroll
    for (int j = 0; j < 8; ++j) {
        int ih = 8*am + j - cl - 3;
        float t = (float)(ih - 5);
        Bh[j] = ((unsigned)ih <= 10u) ? (_Float16)(wp.A * exp2f(-wp.B*t*t))
                                      : (_Float16)0.f;
    }
    f16x4 Av1, Av2;
    #pragma unroll
    for (int j = 0; j < 4; ++j) {
        int k = 4*am + j;
        int i1 = k - cl;
        float t1 = (float)(i1 - 5);
        Av1[j] = ((unsigned)i1 <= 10u) ? (_Float16)(wp.A * exp2f(-wp.B*t1*t1))
                                       : (_Float16)0.f;
        int i2 = k + 16 - cl;
        float t2 = (float)(i2 - 5);
        Av2[j] = ((unsigned)i2 <= 10u) ? (_Float16)(wp.A * exp2f(-wp.B*t2*t2))
                                       : (_Float16)0.f;
    }
    __syncthreads();

    const float C1 = 1e-4f, C2 = 9e-4f;
    float lsum = 0.f;

    for (int g = 0; g < G_TILES; ++g) {
        char* buf = lds + (g & 1) * BUF_B;

        // ---- phase 1: write prefetched tile to buf; issue next prefetch ----
        write_tile(buf);
        if (g + 1 < G_TILES) load_tile(base_t + g + 1);
        barrier_nodrain();             // the ONLY barrier in the loop

        // ---- compute: all-register H+V blur + SSIM (no LDS writes) ----
        {
            const int abase = cl * RAW_STRIDE + 32 * wid + am * 16;
            f16x8 hx3[3], hy3[3];
            #pragma unroll
            for (int mt = 0; mt < 3; ++mt) {
                hx3[mt] = *(const f16x8*)(buf + (16*mt) * RAW_STRIDE + abase);
                hy3[mt] = *(const f16x8*)(buf + RAW_PLANE + (16*mt) * RAW_STRIDE + abase);
            }

            f32x4 accv[4][2];
            #pragma unroll
            for (int q = 0; q < 4; ++q) {
                f32x4 Dh[3];
                #pragma unroll
                for (int mt = 0; mt < 3; ++mt) {
                    f16x8 A = (q == 0) ? hx3[mt]
                            : (q == 1) ? hy3[mt]
                            : (q == 2) ? (f16x8)(hx3[mt]*hx3[mt] + hy3[mt]*hy3[mt])
                                       : (f16x8)(hx3[mt]*hy3[mt]);
                    f32x4 zz = {0.f, 0.f, 0.f, 0.f};
                    Dh[mt] = __builtin_amdgcn_mfma_f32_16x16x32_f16(A, Bh, zz, 0, 0, 0);
                }
                #pragma unroll
                for (int mtv = 0; mtv < 2; ++mtv) {
                    f16x4 B1, B2;
                    #pragma unroll
                    for (int j = 0; j < 4; ++j) {
                        B1[j] = (_Float16)Dh[mtv][j];
                        B2[j] = (_Float16)Dh[mtv+1][j];
                    }
                    f32x4 zz = {0.f, 0.f, 0.f, 0.f};
                    f32x4 acc = __builtin_amdgcn_mfma_f32_16x16x16f16(Av2, B2, zz, 0, 0, 0);
                    accv[q][mtv] = __builtin_amdgcn_mfma_f32_16x16x16f16(Av1, B1, acc, 0, 0, 0);
                }
            }

            #pragma unroll
            for (int mtv = 0; mtv < 2; ++mtv) {
                #pragma unroll
                for (int j = 0; j < 4; ++j) {
                    float mu1 = accv[0][mtv][j], mu2 = accv[1][mtv][j];
                    float bss = accv[2][mtv][j], bxy = accv[3][mtv][j];
                    float mu1s = mu1*mu1, mu2s = mu2*mu2, mu12 = mu1*mu2;
                    float ssum = bss - mu1s - mu2s;
                    float s12  = bxy - mu12;
                    float num = (2.f*mu12 + C1) * (2.f*s12 + C2);
                    float den = (mu1s + mu2s + C1) * (ssum + C2);
                    lsum = fmaf(num, __builtin_amdgcn_rcpf(den), lsum);
                }
            }
        }
        // no trailing barrier: next iteration writes the OTHER buffer
    }

    // ---- block reduction + one atomic ----
    for (int off = 32; off > 0; off >>= 1)
        lsum += __shfl_down(lsum, off, 64);
    if (lane == 0) wsum[wid] = lsum;
    __syncthreads();
    if (tid == 0) {
        float bsum = wsum[0] + wsum[1] + wsum[2] + wsum[3];
        const float invN = 1.0f / (float)((size_t)NPLANES * HH * WW);
        atomicAdd(out, -bsum * invN);
    }
}

extern "C" void kernel_launch(void* const* d_in, const int* in_sizes, int n_in,
                              void* d_out, int out_size, void* d_ws, size_t ws_size,
                              hipStream_t stream) {
    const float* img = (const float*)d_in[0];
    const float* tgt = (const float*)d_in[1];
    float* out = (float*)d_out;

    // g[i] = exp(-(i-5)^2/4.5)/s = A * 2^(-B*(i-5)^2)
    double s = 0.0;
    for (int i = 0; i < 11; ++i) {
        double d = (double)(i - 5);
        s += exp(-(d * d) / 4.5);
    }
    WParam wp;
    wp.A = (float)(1.0 / s);
    wp.B = (float)(M_LOG2E / 4.5);

    ssim_init_out<<<1, 1, 0, stream>>>(out);
    ssim_mfma<<<NBLOCKS, 256, 0, stream>>>(img, tgt, out, wp);
}